// Round 2
// baseline (8254.138 us; speedup 1.0000x reference)
//
#include <hip/hip_runtime.h>
#include <math.h>

#define N_NODES 20000
#define N_EDGES 320000
#define N_GRAPHS 64
#define PD 9
#define KD 32
#define MD 32
#define NK 5
#define EIN 161
#define EIN2 322
#define ALLF (KD*(NK+1))   // 192
#define LN_EPS 1e-5f

__device__ __forceinline__ float silu_f(float x) { return x / (1.f + __expf(-x)); }

// ---------------- node embed: feats = props @ embed_W + b ----------------
__global__ __launch_bounds__(256) void embed_nodes_kernel(
    const float* __restrict__ props, const float* __restrict__ W,
    const float* __restrict__ b, float* __restrict__ feats,
    float* __restrict__ allf)
{
    int t = threadIdx.x;
    int n = blockIdx.x * 8 + (t >> 5);
    int f = t & 31;
    if (n >= N_NODES) return;
    float acc = b[f];
    #pragma unroll
    for (int i = 0; i < PD; ++i) acc += props[n*PD + i] * W[i*KD + f];
    feats[n*KD + f] = acc;
    allf[n*ALLF + f] = acc;
}

// ------- edge prep: edge_feats, rel_dist, deg (atomic count on dst) -------
__global__ __launch_bounds__(256) void edge_prep_kernel(
    const float* __restrict__ edge_props, const float* __restrict__ positions,
    const int* __restrict__ ei, const float* __restrict__ W,
    const float* __restrict__ b, float* __restrict__ edge_feats,
    float* __restrict__ rel_dist, float* __restrict__ deg)
{
    int t = threadIdx.x;
    int e = blockIdx.x * 8 + (t >> 5);
    int f = t & 31;
    if (e >= N_EDGES) return;
    float acc = b[f];
    #pragma unroll
    for (int i = 0; i < PD; ++i) acc += edge_props[e*PD + i] * W[i*KD + f];
    edge_feats[e*KD + f] = acc;
    if (f == 0) {
        int s = ei[e], d = ei[N_EDGES + e];
        float dx = positions[s*3+0] - positions[d*3+0];
        float dy = positions[s*3+1] - positions[d*3+1];
        float dz = positions[s*3+2] - positions[d*3+2];
        rel_dist[e] = dx*dx + dy*dy + dz*dz;
        atomicAdd(&deg[d], 1.f);
    }
}

// ---------------- fused edge MLP + LN + mean-aggregate ----------------
// 32 edges/block. h[32][161] in LDS; W1 tiled 161x32 through LDS;
// 2x2 register micro-tile; fused silu -> W2 -> silu -> LN -> atomicAdd.
__global__ __launch_bounds__(256) void edge_mlp_kernel(
    const float* __restrict__ feats, const float* __restrict__ edge_feats,
    const float* __restrict__ rel_dist, const int* __restrict__ ei,
    const float* __restrict__ eW1, const float* __restrict__ eb1,
    const float* __restrict__ eW2, const float* __restrict__ eb2,
    const float* __restrict__ lg, const float* __restrict__ lb,
    float* __restrict__ msum)
{
    __shared__ float hs[32*161];
    __shared__ float W1l[161*32];
    __shared__ float h1l[32*33];
    __shared__ float ml[32*33];
    __shared__ int dstl[32], srcl[32];
    __shared__ float rdl[32];
    __shared__ float mul[32], rsl[32];

    int t = threadIdx.x;
    int e0g = blockIdx.x * 32;
    if (t < 32) {
        srcl[t] = ei[e0g + t];
        dstl[t] = ei[N_EDGES + e0g + t];
        rdl[t]  = rel_dist[e0g + t];
    }
    __syncthreads();

    // stage h = [feats[dst], feats[src], sin(d/2^i), cos(d/2^i), d, edge_feats]
    for (int idx = t; idx < 32*161; idx += 256) {
        int e = idx / 161;
        int i = idx - e*161;
        float rd = rdl[e];
        float v;
        if (i < 32)        v = feats[dstl[e]*KD + i];
        else if (i < 64)   v = feats[srcl[e]*KD + (i-32)];
        else if (i < 96)   v = sinf(ldexpf(rd, -(i-64)));
        else if (i < 128)  v = cosf(ldexpf(rd, -(i-96)));
        else if (i == 128) v = rd;
        else               v = edge_feats[(e0g+e)*KD + (i-129)];
        hs[idx] = v;
    }

    int ee = 2*(t >> 4);        // edge pair base: 0,2,...,30
    int j0 = 2*(t & 15);        // col pair base:  0,2,...,30
    float m00=0.f, m01=0.f, m10=0.f, m11=0.f;

    for (int jt = 0; jt < EIN2; jt += 32) {
        int jn = min(32, EIN2 - jt);
        __syncthreads();
        for (int idx = t; idx < 161*32; idx += 256) {
            int i = idx >> 5, jj = idx & 31;
            W1l[idx] = (jj < jn) ? eW1[i*EIN2 + jt + jj] : 0.f;
        }
        __syncthreads();
        float a00=0.f, a01=0.f, a10=0.f, a11=0.f;
        const float* h0 = &hs[ee*161];
        const float* h1 = h0 + 161;
        for (int i = 0; i < EIN; ++i) {
            float w0 = W1l[i*32 + j0];
            float w1 = W1l[i*32 + j0 + 1];
            float x0 = h0[i], x1 = h1[i];
            a00 += x0*w0; a01 += x0*w1;
            a10 += x1*w0; a11 += x1*w1;
        }
        if (j0 < jn) {
            float bb = eb1[jt + j0];
            h1l[ee*33 + j0]     = silu_f(a00 + bb);
            h1l[(ee+1)*33 + j0] = silu_f(a10 + bb);
        }
        if (j0 + 1 < jn) {
            float bb = eb1[jt + j0 + 1];
            h1l[ee*33 + j0 + 1]     = silu_f(a01 + bb);
            h1l[(ee+1)*33 + j0 + 1] = silu_f(a11 + bb);
        }
        __syncthreads();
        for (int jj = 0; jj < jn; ++jj) {
            float w0 = eW2[(jt+jj)*MD + j0];
            float w1 = eW2[(jt+jj)*MD + j0 + 1];
            float p0 = h1l[ee*33 + jj];
            float p1 = h1l[(ee+1)*33 + jj];
            m00 += p0*w0; m01 += p0*w1;
            m10 += p1*w0; m11 += p1*w1;
        }
    }

    // m_ij = silu(. + b2), then LayerNorm per edge
    {
        float b0v = eb2[j0], b1v = eb2[j0+1];
        ml[ee*33 + j0]       = silu_f(m00 + b0v);
        ml[ee*33 + j0 + 1]   = silu_f(m01 + b1v);
        ml[(ee+1)*33 + j0]   = silu_f(m10 + b0v);
        ml[(ee+1)*33 + j0+1] = silu_f(m11 + b1v);
    }
    __syncthreads();
    if (t < 32) {
        float s = 0.f;
        for (int c = 0; c < 32; ++c) s += ml[t*33 + c];
        float mu = s * (1.f/32.f);
        float var = 0.f;
        for (int c = 0; c < 32; ++c) { float d = ml[t*33 + c] - mu; var += d*d; }
        var *= (1.f/32.f);
        mul[t] = mu;
        rsl[t] = rsqrtf(var + LN_EPS);
    }
    __syncthreads();
    {
        int d0 = dstl[ee], d1 = dstl[ee+1];
        float g0 = lg[j0], g1 = lg[j0+1], b0v = lb[j0], b1v = lb[j0+1];
        float mu0 = mul[ee], rs0 = rsl[ee], mu1 = mul[ee+1], rs1 = rsl[ee+1];
        atomicAdd(&msum[d0*MD + j0],     (ml[ee*33 + j0]       - mu0)*rs0*g0 + b0v);
        atomicAdd(&msum[d0*MD + j0 + 1], (ml[ee*33 + j0 + 1]   - mu0)*rs0*g1 + b1v);
        atomicAdd(&msum[d1*MD + j0],     (ml[(ee+1)*33 + j0]   - mu1)*rs1*g0 + b0v);
        atomicAdd(&msum[d1*MD + j0 + 1], (ml[(ee+1)*33 + j0+1] - mu1)*rs1*g1 + b1v);
    }
}

// ---------------- node MLP: wave per node ----------------
__global__ __launch_bounds__(256) void node_mlp_kernel(
    const float* __restrict__ msum, const float* __restrict__ deg,
    const float* __restrict__ nW1, const float* __restrict__ nb1,
    const float* __restrict__ nW2, const float* __restrict__ nb2,
    const float* __restrict__ eln_g, const float* __restrict__ eln_b,
    const float* __restrict__ n1g, const float* __restrict__ n1b,
    const float* __restrict__ n2g, const float* __restrict__ n2b,
    float* __restrict__ feats, float* __restrict__ allf, int kslot)
{
    __shared__ float W1l[64*64];
    __shared__ float W2l[64*32];
    int t = threadIdx.x;
    for (int idx = t; idx < 64*64; idx += 256) W1l[idx] = nW1[idx];
    for (int idx = t; idx < 64*32; idx += 256) W2l[idx] = nW2[idx];
    __syncthreads();

    int w = t >> 6, L = t & 63;
    int n = blockIdx.x*4 + w;
    if (n >= N_NODES) return;
    int c = L & 31;

    float x;
    if (L < 32) x = feats[n*KD + L];
    else        x = msum[n*KD + c] / fmaxf(deg[n], 1.f);

    // group LayerNorm over each 32-lane half
    float s = x;
    #pragma unroll
    for (int m = 16; m; m >>= 1) s += __shfl_xor(s, m, 32);
    float mu = s * (1.f/32.f);
    float d = x - mu;
    float v = d*d;
    #pragma unroll
    for (int m = 16; m; m >>= 1) v += __shfl_xor(v, m, 32);
    float rstd = rsqrtf(v * (1.f/32.f) + LN_EPS);
    float g = (L < 32) ? n1g[c] : eln_g[c];
    float bb = (L < 32) ? n1b[c] : eln_b[c];
    float z = d * rstd * g + bb;

    // stage 1: 64 -> 64
    float acc = nb1[L];
    for (int i = 0; i < 64; ++i) {
        float zi = __shfl(z, i, 64);
        acc += zi * W1l[i*64 + L];
    }
    float y = silu_f(acc);

    // stage 2: 64 -> 32 (lanes < 32 hold outputs)
    float acc2 = 0.f;
    if (L < 32) acc2 = nb2[L];
    for (int j = 0; j < 64; ++j) {
        float yj = __shfl(y, j, 64);
        if (L < 32) acc2 += yj * W2l[j*32 + L];
    }

    float s2 = acc2;
    #pragma unroll
    for (int m = 16; m; m >>= 1) s2 += __shfl_xor(s2, m, 32);
    float mu2 = s2 * (1.f/32.f);
    float d2 = acc2 - mu2;
    float v2 = d2*d2;
    #pragma unroll
    for (int m = 16; m; m >>= 1) v2 += __shfl_xor(v2, m, 32);
    float rstd2 = rsqrtf(v2 * (1.f/32.f) + LN_EPS);

    if (L < 32) {
        float h2 = d2 * rstd2 * n2g[L] + n2b[L];
        float nf = feats[n*KD + L] + h2;
        feats[n*KD + L] = nf;
        allf[n*ALLF + kslot*KD + L] = nf;
    }
}

// ---------------- mean pool per graph (batch is sorted) ----------------
__global__ __launch_bounds__(256) void pool_kernel(
    const float* __restrict__ allf, const int* __restrict__ batch,
    float* __restrict__ gvec)
{
    int g = blockIdx.x, t = threadIdx.x;
    int lo = 0, hi = N_NODES;
    while (lo < hi) { int mid = (lo+hi) >> 1; if (batch[mid] < g) lo = mid+1; else hi = mid; }
    int start = lo;
    hi = N_NODES;
    while (lo < hi) { int mid = (lo+hi) >> 1; if (batch[mid] < g+1) lo = mid+1; else hi = mid; }
    int end = lo;
    if (t < ALLF) {
        float acc = 0.f;
        for (int n = start; n < end; ++n) acc += allf[n*ALLF + t];
        float cnt = fmaxf((float)(end - start), 1.f);
        gvec[g*ALLF + t] = acc / cnt;
    }
}

// ---------------- final FNN: block per graph ----------------
__global__ __launch_bounds__(256) void fnn_kernel(
    const float* __restrict__ gvec,
    const float* __restrict__ W0, const float* __restrict__ b0,
    const float* __restrict__ W1, const float* __restrict__ b1,
    const float* __restrict__ W2, const float* __restrict__ b2,
    const float* __restrict__ W3, const float* __restrict__ b3,
    float* __restrict__ out)
{
    __shared__ float xs[256];
    __shared__ float partial[4];
    int g = blockIdx.x, t = threadIdx.x;
    if (t < ALLF) xs[t] = gvec[g*ALLF + t];
    __syncthreads();
    float acc = b0[t];
    for (int i = 0; i < ALLF; ++i) acc += xs[i] * W0[i*256 + t];
    acc = silu_f(acc);
    __syncthreads(); xs[t] = acc; __syncthreads();
    acc = b1[t];
    for (int i = 0; i < 256; ++i) acc += xs[i] * W1[i*256 + t];
    acc = silu_f(acc);
    __syncthreads(); xs[t] = acc; __syncthreads();
    acc = b2[t];
    for (int i = 0; i < 256; ++i) acc += xs[i] * W2[i*256 + t];
    acc = silu_f(acc);
    __syncthreads(); xs[t] = acc; __syncthreads();
    float v = xs[t] * W3[t];
    #pragma unroll
    for (int m = 32; m; m >>= 1) v += __shfl_xor(v, m, 64);
    if ((t & 63) == 0) partial[t >> 6] = v;
    __syncthreads();
    if (t == 0) out[g] = partial[0] + partial[1] + partial[2] + partial[3] + b3[0];
}

extern "C" void kernel_launch(void* const* d_in, const int* in_sizes, int n_in,
                              void* d_out, int out_size, void* d_ws, size_t ws_size,
                              hipStream_t stream) {
    const float* props      = (const float*)d_in[0];
    const float* positions  = (const float*)d_in[1];
    const float* edge_props = (const float*)d_in[2];
    const float* embed_W    = (const float*)d_in[3];
    const float* embed_b    = (const float*)d_in[4];
    const float* eeW        = (const float*)d_in[5];
    const float* eeb        = (const float*)d_in[6];
    const float* k_eW1      = (const float*)d_in[7];
    const float* k_eb1      = (const float*)d_in[8];
    const float* k_eW2      = (const float*)d_in[9];
    const float* k_eb2      = (const float*)d_in[10];
    const float* k_eln_g    = (const float*)d_in[11];
    const float* k_eln_b    = (const float*)d_in[12];
    const float* k_n1g      = (const float*)d_in[13];
    const float* k_n1b      = (const float*)d_in[14];
    const float* k_n2g      = (const float*)d_in[15];
    const float* k_n2b      = (const float*)d_in[16];
    const float* k_nW1      = (const float*)d_in[17];
    const float* k_nb1      = (const float*)d_in[18];
    const float* k_nW2      = (const float*)d_in[19];
    const float* k_nb2      = (const float*)d_in[20];
    const float* fnn_W0     = (const float*)d_in[21];
    const float* fnn_b0     = (const float*)d_in[22];
    const float* fnn_W1     = (const float*)d_in[23];
    const float* fnn_b1     = (const float*)d_in[24];
    const float* fnn_W2     = (const float*)d_in[25];
    const float* fnn_b2     = (const float*)d_in[26];
    const float* fnn_W3     = (const float*)d_in[27];
    const float* fnn_b3     = (const float*)d_in[28];
    const int*   ei         = (const int*)d_in[29];
    const int*   batch      = (const int*)d_in[30];
    float* out = (float*)d_out;

    float* ws    = (float*)d_ws;
    float* feats = ws;                               // N*32
    float* allf  = feats + (size_t)N_NODES*KD;       // N*192
    float* msum  = allf  + (size_t)N_NODES*ALLF;     // N*32
    float* deg   = msum  + (size_t)N_NODES*KD;       // N
    float* rel   = deg   + (size_t)N_NODES;          // E
    float* efeat = rel   + (size_t)N_EDGES;          // E*32
    float* gvec  = efeat + (size_t)N_EDGES*KD;       // G*192

    hipMemsetAsync(deg, 0, N_NODES*sizeof(float), stream);
    embed_nodes_kernel<<<(N_NODES+7)/8, 256, 0, stream>>>(props, embed_W, embed_b, feats, allf);
    edge_prep_kernel<<<(N_EDGES+7)/8, 256, 0, stream>>>(edge_props, positions, ei, eeW, eeb, efeat, rel, deg);

    for (int k = 0; k < NK; ++k) {
        hipMemsetAsync(msum, 0, (size_t)N_NODES*KD*sizeof(float), stream);
        edge_mlp_kernel<<<N_EDGES/32, 256, 0, stream>>>(
            feats, efeat, rel, ei,
            k_eW1 + (size_t)k*EIN*EIN2, k_eb1 + (size_t)k*EIN2,
            k_eW2 + (size_t)k*EIN2*MD,  k_eb2 + (size_t)k*MD,
            k_eln_g + (size_t)k*MD, k_eln_b + (size_t)k*MD, msum);
        node_mlp_kernel<<<N_NODES/4, 256, 0, stream>>>(
            msum, deg,
            k_nW1 + (size_t)k*64*64, k_nb1 + (size_t)k*64,
            k_nW2 + (size_t)k*64*32, k_nb2 + (size_t)k*32,
            k_eln_g + (size_t)k*MD, k_eln_b + (size_t)k*MD,
            k_n1g + (size_t)k*KD, k_n1b + (size_t)k*KD,
            k_n2g + (size_t)k*KD, k_n2b + (size_t)k*KD,
            feats, allf, k+1);
    }

    pool_kernel<<<N_GRAPHS, 256, 0, stream>>>(allf, batch, gvec);
    fnn_kernel<<<N_GRAPHS, 256, 0, stream>>>(gvec, fnn_W0, fnn_b0, fnn_W1, fnn_b1,
                                             fnn_W2, fnn_b2, fnn_W3, fnn_b3, out);
}

// Round 3
// 1442.795 us; speedup vs baseline: 5.7209x; 5.7209x over previous
//
#include <hip/hip_runtime.h>
#include <math.h>

#define N_NODES 20000
#define N_EDGES 320000
#define N_GRAPHS 64
#define PD 9
#define KD 32
#define MD 32
#define NK 5
#define EIN 161
#define EIN2 322
#define ALLF (KD*(NK+1))   // 192
#define LN_EPS 1e-5f

typedef __attribute__((ext_vector_type(8))) short short8;
typedef __attribute__((ext_vector_type(4))) float f32x4;

__device__ __forceinline__ float silu_f(float x) { return x / (1.f + __expf(-x)); }

__device__ __forceinline__ unsigned short f2bf(float x) {
    union { float f; unsigned u; } v; v.f = x;
    unsigned r = v.u + 0x7FFFu + ((v.u >> 16) & 1u);
    return (unsigned short)(r >> 16);
}

// ---------------- weight packing: W1 -> bf16 MFMA B-frag order ----------------
// packed K (160): 0-31 feats_dst, 32-63 feats_src, 64-95 sin, 96-127 cos,
// 128-159 edge_feats (orig rows 129..160). Orig row 128 (rel_dist) handled as
// rank-1 epilogue update. Layout: [k][nt(21)][kb(5)][lane(64)][i(8)]
__global__ __launch_bounds__(256) void pack_w1_kernel(
    const float* __restrict__ eW1, unsigned short* __restrict__ W1p)
{
    int fid = blockIdx.x * 256 + threadIdx.x;
    if (fid >= NK*21*5*64) return;
    int kk = fid / (21*5*64);
    int r  = fid % (21*5*64);
    int nt = r / (5*64);
    int r2 = r % (5*64);
    int kb = r2 >> 6;
    int l  = r2 & 63;
    int q = l >> 4, el = l & 15;
    int n = 16*nt + el;
    short8 out;
    #pragma unroll
    for (int i = 0; i < 8; ++i) {
        int kp = 32*kb + 8*q + i;          // packed k in [0,160)
        int orig = (kp < 128) ? kp : kp + 1; // skip rel_dist row 128
        float v = (n < EIN2) ? eW1[((size_t)kk*EIN + orig)*EIN2 + n] : 0.f;
        out[i] = (short)f2bf(v);
    }
    *(short8*)&W1p[(size_t)fid*8] = out;
}

// W2 packed: K2 = 352 (11 kb blocks; rows >=322 zero). [k][nt2(2)][kb2(11)][lane][i]
__global__ __launch_bounds__(256) void pack_w2_kernel(
    const float* __restrict__ eW2, unsigned short* __restrict__ W2p)
{
    int fid = blockIdx.x * 256 + threadIdx.x;
    if (fid >= NK*2*11*64) return;
    int kk = fid / (2*11*64);
    int r  = fid % (2*11*64);
    int nt2 = r / (11*64);
    int r2  = r % (11*64);
    int kb2 = r2 >> 6;
    int l   = r2 & 63;
    int q = l >> 4, el = l & 15;
    int n = 16*nt2 + el;
    short8 out;
    #pragma unroll
    for (int i = 0; i < 8; ++i) {
        int k2 = 32*kb2 + 8*q + i;
        float v = (k2 < EIN2) ? eW2[((size_t)kk*EIN2 + k2)*MD + n] : 0.f;
        out[i] = (short)f2bf(v);
    }
    *(short8*)&W2p[(size_t)fid*8] = out;
}

// ---------------- node embed + pooled sum slot 0 ----------------
__global__ __launch_bounds__(256) void embed_nodes_kernel(
    const float* __restrict__ props, const float* __restrict__ W,
    const float* __restrict__ b, const int* __restrict__ batch,
    float* __restrict__ feats, unsigned short* __restrict__ feats_bf,
    float* __restrict__ gsum, float* __restrict__ gcnt)
{
    int t = threadIdx.x;
    int n = blockIdx.x * 8 + (t >> 5);
    int f = t & 31;
    if (n >= N_NODES) return;
    float acc = b[f];
    #pragma unroll
    for (int i = 0; i < PD; ++i) acc += props[n*PD + i] * W[i*KD + f];
    feats[n*KD + f] = acc;
    feats_bf[n*KD + f] = f2bf(acc);
    int g = batch[n];
    atomicAdd(&gsum[g*ALLF + f], acc);
    if (f == 0) atomicAdd(&gcnt[g], 1.f);
}

// ------- edge prep (fused): edge embed + rel_dist + deg + constpack -------
// constpack: per 64-edge block b: [w(4)][kbr(3: sin,cos,ef)][lane(64)][i(8)] bf16
__global__ __launch_bounds__(256) void edge_prep_kernel(
    const float* __restrict__ edge_props, const float* __restrict__ positions,
    const int* __restrict__ ei, const float* __restrict__ W,
    const float* __restrict__ b, float* __restrict__ rel,
    float* __restrict__ deg, unsigned short* __restrict__ constpack)
{
    __shared__ float ef[64*32];
    __shared__ float rdl[64];
    int t = threadIdx.x;
    int b0 = blockIdx.x;
    int e0 = b0 * 64;

    // edge embed: thread t -> edge t>>2, cols (t&3)*8..+8
    {
        int e = t >> 2, sub = t & 3;
        float acc[8];
        #pragma unroll
        for (int j = 0; j < 8; ++j) acc[j] = b[sub*8 + j];
        #pragma unroll
        for (int i = 0; i < PD; ++i) {
            float p = edge_props[(size_t)(e0 + e)*PD + i];
            #pragma unroll
            for (int j = 0; j < 8; ++j) acc[j] += p * W[i*KD + sub*8 + j];
        }
        #pragma unroll
        for (int j = 0; j < 8; ++j) ef[e*32 + sub*8 + j] = acc[j];
    }
    if (t < 64) {
        int e = e0 + t;
        int s = ei[e], d = ei[N_EDGES + e];
        float dx = positions[s*3+0] - positions[d*3+0];
        float dy = positions[s*3+1] - positions[d*3+1];
        float dz = positions[s*3+2] - positions[d*3+2];
        float rd = dx*dx + dy*dy + dz*dz;
        rdl[t] = rd;
        rel[e] = rd;
        atomicAdd(&deg[d], 1.f);
    }
    __syncthreads();

    int l = t & 63, w = t >> 6;
    int q = l >> 4, el = l & 15;
    float rd = rdl[16*w + el];
    #pragma unroll
    for (int kbr = 0; kbr < 3; ++kbr) {
        short8 out;
        #pragma unroll
        for (int i = 0; i < 8; ++i) {
            int k = 8*q + i;
            float v;
            if (kbr == 0)      v = sinf(ldexpf(rd, -k));
            else if (kbr == 1) v = cosf(ldexpf(rd, -k));
            else               v = ef[(16*w + el)*32 + k];
            out[i] = (short)f2bf(v);
        }
        *(short8*)&constpack[((((size_t)b0*4 + w)*3 + kbr)*64 + l)*8] = out;
    }
}

// ---------------- MFMA edge MLP + LN + aggregate ----------------
// 64 edges/block, 4 waves x 16 edges. GEMM1: M16 x N336 x K160 per wave,
// rank-1 rel_dist update in epilogue; h1 -> LDS in A-frag layout; GEMM2 K352 N32.
__global__ __launch_bounds__(256) void edge_mlp_mfma(
    const unsigned short* __restrict__ feats_bf,
    const unsigned short* __restrict__ constpack,
    const float* __restrict__ rel, const int* __restrict__ ei,
    const unsigned short* __restrict__ W1p, const unsigned short* __restrict__ W2p,
    const float* __restrict__ eW1k, const float* __restrict__ eb1,
    const float* __restrict__ eb2, const float* __restrict__ lg,
    const float* __restrict__ lb, float* __restrict__ msum)
{
    __shared__ unsigned short hs2[4*11*64*8];   // 45056 B
    __shared__ int dstl[64], srcl[64];
    __shared__ float rdl[64];

    int t = threadIdx.x;
    int b = blockIdx.x;
    int e0 = b * 64;
    if (t < 64) {
        srcl[t] = ei[e0 + t];
        dstl[t] = ei[N_EDGES + e0 + t];
        rdl[t]  = rel[e0 + t];
    }
    // zero K2 pad region (k2 in [336,352): kb2=10, lanes 32..63) for all waves
    if (t < 128) {
        int w = t >> 5, lane = 32 + (t & 31);
        short8 z = {0,0,0,0,0,0,0,0};
        *(short8*)&hs2[((w*11 + 10)*64 + lane)*8] = z;
    }
    __syncthreads();

    int w = t >> 6, l = t & 63, q = l >> 4, el = l & 15;

    // A fragments (5 x short8): dst-feats, src-feats, sin, cos, edge-embed
    short8 a0 = *(const short8*)&feats_bf[(size_t)dstl[16*w + el]*KD + 8*q];
    short8 a1 = *(const short8*)&feats_bf[(size_t)srcl[16*w + el]*KD + 8*q];
    short8 a2 = *(const short8*)&constpack[((((size_t)b*4 + w)*3 + 0)*64 + l)*8];
    short8 a3 = *(const short8*)&constpack[((((size_t)b*4 + w)*3 + 1)*64 + l)*8];
    short8 a4 = *(const short8*)&constpack[((((size_t)b*4 + w)*3 + 2)*64 + l)*8];
    float rdv[4];
    #pragma unroll
    for (int j = 0; j < 4; ++j) rdv[j] = rdl[16*w + 4*q + j];

    const float* w1rd = eW1k + 128*EIN2;  // rel_dist row of W1

    for (int nt = 0; nt < 21; ++nt) {
        f32x4 acc = {0.f, 0.f, 0.f, 0.f};
        const unsigned short* wb = &W1p[(size_t)(nt*5)*512 + (size_t)l*8];
        acc = __builtin_amdgcn_mfma_f32_16x16x32_bf16(a0, *(const short8*)&wb[0*512], acc, 0, 0, 0);
        acc = __builtin_amdgcn_mfma_f32_16x16x32_bf16(a1, *(const short8*)&wb[1*512], acc, 0, 0, 0);
        acc = __builtin_amdgcn_mfma_f32_16x16x32_bf16(a2, *(const short8*)&wb[2*512], acc, 0, 0, 0);
        acc = __builtin_amdgcn_mfma_f32_16x16x32_bf16(a3, *(const short8*)&wb[3*512], acc, 0, 0, 0);
        acc = __builtin_amdgcn_mfma_f32_16x16x32_bf16(a4, *(const short8*)&wb[4*512], acc, 0, 0, 0);
        int n1 = 16*nt + el;
        bool valid = n1 < EIN2;
        float bb = valid ? eb1[n1] : 0.f;
        float wr = valid ? w1rd[n1] : 0.f;
        int kb2 = n1 >> 5, q2 = (n1 >> 3) & 3, i2 = n1 & 7;
        #pragma unroll
        for (int j = 0; j < 4; ++j) {
            float v = acc[j] + bb + rdv[j] * wr;   // rank-1 rel_dist term
            v = silu_f(v);
            unsigned short bv = valid ? f2bf(v) : (unsigned short)0;
            int lane2 = q2*16 + 4*q + j;
            hs2[((w*11 + kb2)*64 + lane2)*8 + i2] = bv;
        }
    }
    __syncthreads();

    f32x4 acc20 = {0.f, 0.f, 0.f, 0.f};
    f32x4 acc21 = {0.f, 0.f, 0.f, 0.f};
    #pragma unroll
    for (int kb2 = 0; kb2 < 11; ++kb2) {
        short8 av = *(const short8*)&hs2[((w*11 + kb2)*64 + l)*8];
        short8 b0 = *(const short8*)&W2p[(size_t)(0*11 + kb2)*512 + (size_t)l*8];
        short8 b1 = *(const short8*)&W2p[(size_t)(1*11 + kb2)*512 + (size_t)l*8];
        acc20 = __builtin_amdgcn_mfma_f32_16x16x32_bf16(av, b0, acc20, 0, 0, 0);
        acc21 = __builtin_amdgcn_mfma_f32_16x16x32_bf16(av, b1, acc21, 0, 0, 0);
    }

    // epilogue: silu -> per-edge LayerNorm (32 cols) -> atomic aggregate
    float e20 = eb2[el], e21 = eb2[16 + el];
    float g0 = lg[el],  g1 = lg[16 + el];
    float bb0 = lb[el], bb1 = lb[16 + el];
    float m0[4], m1[4];
    #pragma unroll
    for (int j = 0; j < 4; ++j) {
        m0[j] = silu_f(acc20[j] + e20);
        m1[j] = silu_f(acc21[j] + e21);
    }
    #pragma unroll
    for (int j = 0; j < 4; ++j) {
        float s = m0[j] + m1[j];
        s += __shfl_xor(s, 1, 16); s += __shfl_xor(s, 2, 16);
        s += __shfl_xor(s, 4, 16); s += __shfl_xor(s, 8, 16);
        float mu = s * (1.f/32.f);
        float d0 = m0[j] - mu, d1 = m1[j] - mu;
        float vv = d0*d0 + d1*d1;
        vv += __shfl_xor(vv, 1, 16); vv += __shfl_xor(vv, 2, 16);
        vv += __shfl_xor(vv, 4, 16); vv += __shfl_xor(vv, 8, 16);
        float rs = rsqrtf(vv * (1.f/32.f) + LN_EPS);
        int dst = dstl[16*w + 4*q + j];
        atomicAdd(&msum[(size_t)dst*MD + el],      d0*rs*g0 + bb0);
        atomicAdd(&msum[(size_t)dst*MD + 16 + el], d1*rs*g1 + bb1);
    }
}

// ---------------- node MLP: wave per node ----------------
__global__ __launch_bounds__(256) void node_mlp_kernel(
    const float* __restrict__ msum, const float* __restrict__ deg,
    const float* __restrict__ nW1, const float* __restrict__ nb1,
    const float* __restrict__ nW2, const float* __restrict__ nb2,
    const float* __restrict__ eln_g, const float* __restrict__ eln_b,
    const float* __restrict__ n1g, const float* __restrict__ n1b,
    const float* __restrict__ n2g, const float* __restrict__ n2b,
    const int* __restrict__ batch,
    float* __restrict__ feats, unsigned short* __restrict__ feats_bf,
    float* __restrict__ gsum, int kslot)
{
    __shared__ float W1l[64*64];
    __shared__ float W2l[64*32];
    int t = threadIdx.x;
    for (int idx = t; idx < 64*64; idx += 256) W1l[idx] = nW1[idx];
    for (int idx = t; idx < 64*32; idx += 256) W2l[idx] = nW2[idx];
    __syncthreads();

    int w = t >> 6, L = t & 63;
    int n = blockIdx.x*4 + w;
    if (n >= N_NODES) return;
    int c = L & 31;

    float x;
    if (L < 32) x = feats[n*KD + L];
    else        x = msum[n*KD + c] / fmaxf(deg[n], 1.f);

    float s = x;
    #pragma unroll
    for (int m = 16; m; m >>= 1) s += __shfl_xor(s, m, 32);
    float mu = s * (1.f/32.f);
    float d = x - mu;
    float v = d*d;
    #pragma unroll
    for (int m = 16; m; m >>= 1) v += __shfl_xor(v, m, 32);
    float rstd = rsqrtf(v * (1.f/32.f) + LN_EPS);
    float g = (L < 32) ? n1g[c] : eln_g[c];
    float bb = (L < 32) ? n1b[c] : eln_b[c];
    float z = d * rstd * g + bb;

    float acc = nb1[L];
    for (int i = 0; i < 64; ++i) {
        float zi = __shfl(z, i, 64);
        acc += zi * W1l[i*64 + L];
    }
    float y = silu_f(acc);

    float acc2 = 0.f;
    if (L < 32) acc2 = nb2[L];
    for (int j = 0; j < 64; ++j) {
        float yj = __shfl(y, j, 64);
        if (L < 32) acc2 += yj * W2l[j*32 + L];
    }

    float s2 = acc2;
    #pragma unroll
    for (int m = 16; m; m >>= 1) s2 += __shfl_xor(s2, m, 32);
    float mu2 = s2 * (1.f/32.f);
    float d2 = acc2 - mu2;
    float v2 = d2*d2;
    #pragma unroll
    for (int m = 16; m; m >>= 1) v2 += __shfl_xor(v2, m, 32);
    float rstd2 = rsqrtf(v2 * (1.f/32.f) + LN_EPS);

    if (L < 32) {
        float h2 = d2 * rstd2 * n2g[L] + n2b[L];
        float nf = feats[n*KD + L] + h2;
        feats[n*KD + L] = nf;
        feats_bf[n*KD + L] = f2bf(nf);
        atomicAdd(&gsum[batch[n]*ALLF + kslot*KD + L], nf);
    }
}

// ---------------- final FNN: block per graph ----------------
__global__ __launch_bounds__(256) void fnn_kernel(
    const float* __restrict__ gsum, const float* __restrict__ gcnt,
    const float* __restrict__ W0, const float* __restrict__ b0,
    const float* __restrict__ W1, const float* __restrict__ b1,
    const float* __restrict__ W2, const float* __restrict__ b2,
    const float* __restrict__ W3, const float* __restrict__ b3,
    float* __restrict__ out)
{
    __shared__ float xs[256];
    __shared__ float partial[4];
    int g = blockIdx.x, t = threadIdx.x;
    float inv = 1.f / fmaxf(gcnt[g], 1.f);
    if (t < ALLF) xs[t] = gsum[g*ALLF + t] * inv;
    __syncthreads();
    float acc = b0[t];
    for (int i = 0; i < ALLF; ++i) acc += xs[i] * W0[i*256 + t];
    acc = silu_f(acc);
    __syncthreads(); xs[t] = acc; __syncthreads();
    acc = b1[t];
    for (int i = 0; i < 256; ++i) acc += xs[i] * W1[i*256 + t];
    acc = silu_f(acc);
    __syncthreads(); xs[t] = acc; __syncthreads();
    acc = b2[t];
    for (int i = 0; i < 256; ++i) acc += xs[i] * W2[i*256 + t];
    acc = silu_f(acc);
    __syncthreads(); xs[t] = acc; __syncthreads();
    float v = xs[t] * W3[t];
    #pragma unroll
    for (int m = 32; m; m >>= 1) v += __shfl_xor(v, m, 64);
    if ((t & 63) == 0) partial[t >> 6] = v;
    __syncthreads();
    if (t == 0) out[g] = partial[0] + partial[1] + partial[2] + partial[3] + b3[0];
}

extern "C" void kernel_launch(void* const* d_in, const int* in_sizes, int n_in,
                              void* d_out, int out_size, void* d_ws, size_t ws_size,
                              hipStream_t stream) {
    const float* props      = (const float*)d_in[0];
    const float* positions  = (const float*)d_in[1];
    const float* edge_props = (const float*)d_in[2];
    const float* embed_W    = (const float*)d_in[3];
    const float* embed_b    = (const float*)d_in[4];
    const float* eeW        = (const float*)d_in[5];
    const float* eeb        = (const float*)d_in[6];
    const float* k_eW1      = (const float*)d_in[7];
    const float* k_eb1      = (const float*)d_in[8];
    const float* k_eW2      = (const float*)d_in[9];
    const float* k_eb2      = (const float*)d_in[10];
    const float* k_eln_g    = (const float*)d_in[11];
    const float* k_eln_b    = (const float*)d_in[12];
    const float* k_n1g      = (const float*)d_in[13];
    const float* k_n1b      = (const float*)d_in[14];
    const float* k_n2g      = (const float*)d_in[15];
    const float* k_n2b      = (const float*)d_in[16];
    const float* k_nW1      = (const float*)d_in[17];
    const float* k_nb1      = (const float*)d_in[18];
    const float* k_nW2      = (const float*)d_in[19];
    const float* k_nb2      = (const float*)d_in[20];
    const float* fnn_W0     = (const float*)d_in[21];
    const float* fnn_b0     = (const float*)d_in[22];
    const float* fnn_W1     = (const float*)d_in[23];
    const float* fnn_b1     = (const float*)d_in[24];
    const float* fnn_W2     = (const float*)d_in[25];
    const float* fnn_b2     = (const float*)d_in[26];
    const float* fnn_W3     = (const float*)d_in[27];
    const float* fnn_b3     = (const float*)d_in[28];
    const int*   ei         = (const int*)d_in[29];
    const int*   batch      = (const int*)d_in[30];
    float* out = (float*)d_out;

    // ---- workspace layout (bytes, 256-aligned) ----
    char* wsb = (char*)d_ws;
    size_t off = 0;
    #define WS_ALLOC(ptr_t, name, bytes) ptr_t name = (ptr_t)(wsb + off); off += (((size_t)(bytes)) + 255) & ~(size_t)255;
    WS_ALLOC(float*, feats, (size_t)N_NODES*KD*4)
    WS_ALLOC(float*, msum,  (size_t)N_NODES*KD*4)
    WS_ALLOC(float*, deg,   (size_t)N_NODES*4)
    WS_ALLOC(float*, rel,   (size_t)N_EDGES*4)
    WS_ALLOC(float*, gsum,  (size_t)N_GRAPHS*ALLF*4)
    WS_ALLOC(float*, gcnt,  (size_t)N_GRAPHS*4)
    WS_ALLOC(unsigned short*, feats_bf,  (size_t)N_NODES*KD*2)
    WS_ALLOC(unsigned short*, constpack, (size_t)5000*4*3*64*8*2)   // 61.44 MB
    WS_ALLOC(unsigned short*, W1p, (size_t)NK*21*5*64*8*2)
    WS_ALLOC(unsigned short*, W2p, (size_t)NK*2*11*64*8*2)
    (void)ws_size;

    hipMemsetAsync(deg,  0, (size_t)N_NODES*4, stream);
    hipMemsetAsync(gsum, 0, (size_t)N_GRAPHS*ALLF*4, stream);
    hipMemsetAsync(gcnt, 0, (size_t)N_GRAPHS*4, stream);

    pack_w1_kernel<<<(NK*21*5*64 + 255)/256, 256, 0, stream>>>(k_eW1, W1p);
    pack_w2_kernel<<<(NK*2*11*64 + 255)/256, 256, 0, stream>>>(k_eW2, W2p);
    embed_nodes_kernel<<<N_NODES/8, 256, 0, stream>>>(props, embed_W, embed_b, batch,
                                                      feats, feats_bf, gsum, gcnt);
    edge_prep_kernel<<<N_EDGES/64, 256, 0, stream>>>(edge_props, positions, ei, eeW, eeb,
                                                     rel, deg, constpack);

    for (int k = 0; k < NK; ++k) {
        hipMemsetAsync(msum, 0, (size_t)N_NODES*KD*4, stream);
        edge_mlp_mfma<<<N_EDGES/64, 256, 0, stream>>>(
            feats_bf, constpack, rel, ei,
            W1p + (size_t)k*21*5*512, W2p + (size_t)k*2*11*512,
            k_eW1 + (size_t)k*EIN*EIN2,
            k_eb1 + (size_t)k*EIN2, k_eb2 + (size_t)k*MD,
            k_eln_g + (size_t)k*MD, k_eln_b + (size_t)k*MD, msum);
        node_mlp_kernel<<<N_NODES/4, 256, 0, stream>>>(
            msum, deg,
            k_nW1 + (size_t)k*64*64, k_nb1 + (size_t)k*64,
            k_nW2 + (size_t)k*64*32, k_nb2 + (size_t)k*32,
            k_eln_g + (size_t)k*MD, k_eln_b + (size_t)k*MD,
            k_n1g + (size_t)k*KD, k_n1b + (size_t)k*KD,
            k_n2g + (size_t)k*KD, k_n2b + (size_t)k*KD,
            batch, feats, feats_bf, gsum, k+1);
    }

    fnn_kernel<<<N_GRAPHS, 256, 0, stream>>>(gsum, gcnt, fnn_W0, fnn_b0, fnn_W1, fnn_b1,
                                             fnn_W2, fnn_b2, fnn_W3, fnn_b3, out);
}